// Round 9
// baseline (222.464 us; speedup 1.0000x reference)
//
#include <hip/hip_runtime.h>
#include <hip/hip_bf16.h>

typedef unsigned short u16;
typedef unsigned int u32;
typedef __attribute__((ext_vector_type(8))) short bf16x8;  // 8 bf16 (4 VGPRs)
typedef __attribute__((ext_vector_type(4))) short bf16x4;  // 4 bf16 (2 VGPRs)
typedef __attribute__((ext_vector_type(4))) float f32x4;

#define DEVI __device__ __forceinline__

DEVI u16 f2bf(float f) {
  union { float f; unsigned int u; } v; v.f = f;
  unsigned int u = v.u;
  unsigned int r = (u + 0x7fffu + ((u >> 16) & 1u)) >> 16;  // RNE
  return (u16)r;
}

DEVI float bf2f(u16 b) {
  union { unsigned int u; float f; } v; v.u = ((unsigned int)b) << 16;
  return v.f;
}

DEVI float fexp2(float x) {
#if __has_builtin(__builtin_amdgcn_exp2f)
  return __builtin_amdgcn_exp2f(x);
#else
  return exp2f(x);
#endif
}

// pack two fp32 -> two bf16 (round +half) in one u32: b -> low16, a -> high16
DEVI u32 pkbf(float a, float b) {
  union { float f; u32 u; } ua, ub;
  ua.f = a; ub.f = b;
  return __builtin_amdgcn_perm(ua.u + 0x8000u, ub.u + 0x8000u, 0x07060302u);
}

// async global->LDS, 16B per lane; LDS dest = uniform base + lane*16
DEVI void lds_cp16(u16* lds, const u16* g) {
  __builtin_amdgcn_global_load_lds(
      (const __attribute__((address_space(1))) u32*)g,
      (__attribute__((address_space(3))) u32*)lds, 16, 0, 0);
}

DEVI f32x4 mfma16x16x16_bf16(bf16x4 a, bf16x4 b, f32x4 c) {
#if __has_builtin(__builtin_amdgcn_mfma_f32_16x16x16bf16_1k)
  return __builtin_amdgcn_mfma_f32_16x16x16bf16_1k(a, b, c, 0, 0, 0);
#else
  f32x4 d;
  asm volatile("v_mfma_f32_16x16x16_bf16 %0, %1, %2, %3"
               : "=v"(d) : "v"(a), "v"(b), "v"(c));
  return d;
#endif
}

// ---------------- fp32 -> bf16 conversion (x, w_in, w_out merged) ----------------
__global__ __launch_bounds__(256) void cvt_all(
    const float4* __restrict__ x, const float4* __restrict__ wi,
    const float4* __restrict__ wo, u16* __restrict__ xb,
    u16* __restrict__ wib, u16* __restrict__ wob) {
  int i = blockIdx.x * 256 + threadIdx.x;
  const float4* src; u16* dst; int off;
  if (i < 524288)      { src = x;  dst = xb;  off = i; }
  else if (i < 720896) { src = wi; dst = wib; off = i - 524288; }
  else                 { src = wo; dst = wob; off = i - 720896; }
  float4 f = src[off];
  ushort4 o;
  o.x = f2bf(f.x); o.y = f2bf(f.y); o.z = f2bf(f.z); o.w = f2bf(f.w);
  ((ushort4*)dst)[off] = o;
}

// ---------------- in_proj GEMM: qvk = x @ w_in^T + b_in (R3-proven config) ----------------
// Q is PRE-SCALED by (1/sqrt(64))*log2(e) so attention scores come out in
// exp2 domain with no per-score multiply.
__global__ __launch_bounds__(256) void inproj_gemm(
    const u16* __restrict__ xb, const u16* __restrict__ wb,
    const float* __restrict__ bin,
    u16* __restrict__ Qb, u16* __restrict__ Kb, u16* __restrict__ Vt) {
  const int K = 512;
  const float SCL = 0.180336878f;  // (1/sqrt(64)) * log2(e)
  __shared__ u16 At[2][128 * 32];
  __shared__ u16 Bt[2][128 * 32];
  int tid = threadIdx.x;
  int w = tid >> 6, lane = tid & 63;
  int ql = lane & 15, quad = lane >> 4;
  int wr = w >> 1, wc = w & 1;
  int mtile = blockIdx.x * 128, ntile = blockIdx.y * 128;

  int r4 = lane >> 2, c4 = lane & 3;
  int swz4 = c4 ^ (r4 & 3);

  const u16* ag0 = xb + (size_t)(mtile + w * 32 + r4) * K + swz4 * 8;
  const u16* bg0 = wb + (size_t)(ntile + w * 32 + r4) * K + swz4 * 8;

  f32x4 acc[4][4];
#pragma unroll
  for (int t = 0; t < 4; ++t)
#pragma unroll
    for (int u = 0; u < 4; ++u) acc[t][u] = (f32x4){0, 0, 0, 0};

  lds_cp16(&At[0][w * 1024], ag0);
  lds_cp16(&At[0][w * 1024 + 512], ag0 + 16 * K);
  lds_cp16(&Bt[0][w * 1024], bg0);
  lds_cp16(&Bt[0][w * 1024 + 512], bg0 + 16 * K);

  int cb = ql & 3;
  for (int kk = 0; kk < 16; ++kk) {
    int cur = kk & 1;
    __syncthreads();
    if (kk < 15) {
      int k0 = (kk + 1) * 32;
      lds_cp16(&At[cur ^ 1][w * 1024], ag0 + k0);
      lds_cp16(&At[cur ^ 1][w * 1024 + 512], ag0 + 16 * K + k0);
      lds_cp16(&Bt[cur ^ 1][w * 1024], bg0 + k0);
      lds_cp16(&Bt[cur ^ 1][w * 1024 + 512], bg0 + 16 * K + k0);
    }
    bf16x8 af[4], bf[4];
#pragma unroll
    for (int t = 0; t < 4; ++t) {
      int row = wr * 64 + t * 16 + ql;
      af[t] = *(const bf16x8*)(&At[cur][row * 32 + ((quad ^ cb) * 8)]);
    }
#pragma unroll
    for (int u = 0; u < 4; ++u) {
      int row = wc * 64 + u * 16 + ql;
      bf[u] = *(const bf16x8*)(&Bt[cur][row * 32 + ((quad ^ cb) * 8)]);
    }
#pragma unroll
    for (int t = 0; t < 4; ++t)
#pragma unroll
      for (int u = 0; u < 4; ++u)
        acc[t][u] = __builtin_amdgcn_mfma_f32_16x16x32_bf16(af[t], bf[u], acc[t][u], 0, 0, 0);
  }

#pragma unroll
  for (int u = 0; u < 4; ++u) {
    int n = ntile + wc * 64 + u * 16 + ql;
    float bias = bin[n];
    int chunk = n >> 9;       // 0=q, 1=v, 2=k
    int nc = n & 511;
    int h = nc >> 6, d = nc & 63;
#pragma unroll
    for (int t = 0; t < 4; ++t)
#pragma unroll
      for (int r = 0; r < 4; ++r) {
        int m = mtile + wr * 64 + t * 16 + quad * 4 + r;
        int b = m >> 11, s = m & 2047;
        float v = acc[t][u][r] + bias;
        int bh = b * 8 + h;
        if (chunk == 0)      Qb[((size_t)bh * 2048 + s) * 64 + d] = f2bf(v * SCL);
        else if (chunk == 2) Kb[((size_t)bh * 2048 + s) * 64 + d] = f2bf(v);
        else                 Vt[((size_t)bh * 64 + d) * 2048 + s] = f2bf(v);
      }
  }
}

// ---------------- flash attention (causal): wave-per-key-slice, A/B phases ----------------
// Pair j = tiles A=j, B=31-j; 33 items split 11/11/11 across 3 chunk-WGs
// (grid 16x3x16). Within a WG (4 waves), wave w owns keys [16w,16w+16) of
// every staged 64-key block and computes partial O^T over ALL 64 q-rows of
// the current tile (Q in registers). 4x fewer LDS reads per wave than the
// q-split design; all 16 PV MFMAs per item hit distinct accumulators.
// Chunk items: A-items (kb=i) while i<=j, then B-items (kb=i-j-1); phase
// switch flushes (cross-wave O merge via LDS rotating-quarter accumulate)
// and reloads Q. Fixed-max softmax (exp2 domain, Q pre-scaled).
__global__ __launch_bounds__(256, 3) void attn_kernel(
    const u16* __restrict__ Qb, const u16* __restrict__ Kb,
    const u16* __restrict__ Vt, u16* __restrict__ Pp, float* __restrict__ Ml) {
  const int S = 2048;
  __shared__ u16 Kt[2][4096];      // [buf][64 keys x 64 dh], 16B chunks swizzled
  __shared__ u16 Vl[2][4096];      // [buf][64 dh x 64 keys], swizzled
  __shared__ float Mg[64 * 66];    // O merge buffer [q][d], stride 66
  __shared__ float Lg[4][64];      // per-wave l partials [w][q]
  int tid = threadIdx.x;
  int w = tid >> 6, lane = tid & 63;
  int ql = lane & 15, quad = lane >> 4;
  int j = blockIdx.x, c = blockIdx.y, bh = blockIdx.z;
  int tileA = j, tileB = 31 - j;
  const u16* Qh = Qb + (size_t)bh * S * 64;
  const u16* Kh = Kb + (size_t)bh * S * 64;
  const u16* Vh = Vt + (size_t)bh * 64 * S;
  int r8 = lane >> 3, c8 = lane & 7;
  int swz = c8 ^ r8;
  int cb = ql & 7;

  int rsw = j + 1 - c * 11;        // rounds < rsw are tile A
  if (rsw < 0) rsw = 0;
  if (rsw > 11) rsw = 11;

  bf16x8 qf[4][2];                 // Q fragments: [q-tile][dh half]
  f32x4 o[4][4];                   // O^T accum: [d-tile][q-tile]
  float l[4];                      // per-lane l per q-tile (q = ql)

  auto loadQ = [&](int tile) {
    const u16* qp = Qh + (size_t)(tile * 64 + ql) * 64 + quad * 8;
#pragma unroll
    for (int qt = 0; qt < 4; ++qt) {
      qf[qt][0] = *(const bf16x8*)(qp + qt * 1024);
      qf[qt][1] = *(const bf16x8*)(qp + qt * 1024 + 32);
    }
  };
  auto zeroAcc = [&]() {
#pragma unroll
    for (int dt = 0; dt < 4; ++dt)
#pragma unroll
      for (int qt = 0; qt < 4; ++qt) o[dt][qt] = (f32x4){0, 0, 0, 0};
#pragma unroll
    for (int qt = 0; qt < 4; ++qt) l[qt] = 0.0f;
  };
  auto stage = [&](int buf, int kbase) {
    const u16* kg = Kh + (size_t)(kbase + w * 16 + r8) * 64 + swz * 8;
    lds_cp16(&Kt[buf][w * 1024], kg);
    lds_cp16(&Kt[buf][w * 1024 + 512], kg + 8 * 64);
    const u16* vg = Vh + (size_t)(w * 16 + r8) * S + kbase + swz * 8;
    lds_cp16(&Vl[buf][w * 1024], vg);
    lds_cp16(&Vl[buf][w * 1024 + 512], vg + 8 * S);
  };
  auto process = [&](int cur, int kbase, int tile) {
    // S^T = K_slice x Q : A = K rows (w*16+ql), B = Q fragments
    const u16* kr = &Kt[cur][(w * 16 + ql) * 64];
    bf16x8 kf0 = *(const bf16x8*)(kr + ((quad ^ cb) * 8));          // dh 0..31
    bf16x8 kf1 = *(const bf16x8*)(kr + (((quad + 4) ^ cb) * 8));    // dh 32..63
    f32x4 s[4];
#pragma unroll
    for (int qt = 0; qt < 4; ++qt) {
      f32x4 t = {0, 0, 0, 0};
      t = __builtin_amdgcn_mfma_f32_16x16x32_bf16(kf0, qf[qt][0], t, 0, 0, 0);
      t = __builtin_amdgcn_mfma_f32_16x16x32_bf16(kf1, qf[qt][1], t, 0, 0, 0);
      s[qt] = t;
    }
    bool needmask = (kbase == tile * 64);   // only the diagonal block masks
    float e[4][4];
#pragma unroll
    for (int qt = 0; qt < 4; ++qt)
#pragma unroll
      for (int r = 0; r < 4; ++r) {
        float v = s[qt][r];
        if (needmask) {
          int key = w * 16 + quad * 4 + r;   // relative to block
          int qq = qt * 16 + ql;             // relative to tile
          if (key > qq) v = -3.0e38f;        // exp2 -> 0
        }
        e[qt][r] = fexp2(v);
      }
#pragma unroll
    for (int qt = 0; qt < 4; ++qt)
      l[qt] += (e[qt][0] + e[qt][1]) + (e[qt][2] + e[qt][3]);
    bf16x4 p[4];
#pragma unroll
    for (int qt = 0; qt < 4; ++qt) {
      union { bf16x4 v; u32 u[2]; } pk;
      pk.u[0] = pkbf(e[qt][1], e[qt][0]);
      pk.u[1] = pkbf(e[qt][3], e[qt][2]);
      p[qt] = pk.v;
    }
    // O^T += V^T_slice x P^T : 16 independent accumulators
#pragma unroll
    for (int dt = 0; dt < 4; ++dt) {
      const u16* vr = &Vl[cur][(dt * 16 + ql) * 64];
      bf16x4 vf = *(const bf16x4*)(vr + (((w * 2 + (quad >> 1)) ^ cb) * 8 + (quad & 1) * 4));
#pragma unroll
      for (int qt = 0; qt < 4; ++qt)
        o[dt][qt] = mfma16x16x16_bf16(vf, p[qt], o[dt][qt]);
    }
  };
  auto flush = [&](int t01) {
    // l: reduce across quads (each quad holds 4 keys' worth)
    float lv[4];
#pragma unroll
    for (int qt = 0; qt < 4; ++qt) {
      float x = l[qt];
      x += __shfl_xor(x, 16);
      x += __shfl_xor(x, 32);
      lv[qt] = x;
    }
    if (quad == 0) {
#pragma unroll
      for (int qt = 0; qt < 4; ++qt) Lg[w][qt * 16 + ql] = lv[qt];
    }
    // O: rotating-quarter accumulate into Mg
#pragma unroll
    for (int st = 0; st < 4; ++st) {
      __syncthreads();
      int dt = (w + st) & 3;
#pragma unroll
      for (int qt = 0; qt < 4; ++qt) {
        float* mg = &Mg[(qt * 16 + ql) * 66 + dt * 16 + quad * 4];
        f32x4 val = o[dt][qt];
        if (st) {
          f32x4 old = *(const f32x4*)mg;
          val = val + old;
        }
        *(f32x4*)mg = val;
      }
    }
    __syncthreads();
    // write partial O (bf16) + l to global
    int q = tid >> 2, ds = (tid & 3) * 16;
    size_t base = (((size_t)c * 16 + bh) * 16 + j) * 2 + t01;
    if ((tid & 3) == 0)
      Ml[base * 64 + q] = Lg[0][q] + Lg[1][q] + Lg[2][q] + Lg[3][q];
    const float* mrow = &Mg[q * 66 + ds];
    union { bf16x8 v; u16 e[8]; } o0, o1;
#pragma unroll
    for (int i = 0; i < 8; ++i) {
      o0.e[i] = f2bf(mrow[i]);
      o1.e[i] = f2bf(mrow[i + 8]);
    }
    u16* pp = Pp + base * 4096 + q * 64 + ds;
    *(bf16x8*)pp = o0.v;
    *(bf16x8*)(pp + 8) = o1.v;
    __syncthreads();   // Mg/Lg safe to reuse
  };

  // prologue
  int i0 = c * 11;
  int kb0 = (i0 <= j) ? i0 : (i0 - j - 1);
  stage(0, kb0 * 64);
  loadQ(rsw > 0 ? tileA : tileB);
  zeroAcc();

  for (int r = 0; r < 11; ++r) {
    int cur = r & 1;
    __syncthreads();   // staging of cur drained
    if (r == rsw && r > 0) {   // phase switch A -> B (rsw in 1..10)
      flush(0);
      loadQ(tileB);
      zeroAcc();
    }
    if (r < 10) {
      int i1 = c * 11 + r + 1;
      int kb = (i1 <= j) ? i1 : (i1 - j - 1);
      stage(cur ^ 1, kb * 64);
    }
    int i = c * 11 + r;
    int kb = (i <= j) ? i : (i - j - 1);
    process(cur, kb * 64, (r < rsw) ? tileA : tileB);
  }
  flush(rsw >= 11 ? 0 : 1);
  // zero l for phases this chunk never ran (merge kernel skips l==0)
  size_t mb = ((((size_t)c * 16 + bh) * 16 + j) * 2) * 64;
  if (rsw <= 0 && tid < 64) Ml[mb + tid] = 0.0f;
  if (rsw >= 11 && tid < 64) Ml[mb + 64 + tid] = 0.0f;
}

// ---------------- merge <=3 chunk partial sums per row -> Ob ----------------
__global__ __launch_bounds__(256) void attn_merge(
    const u16* __restrict__ Pp, const float* __restrict__ Ml,
    u16* __restrict__ Ob) {
  int tid = threadIdx.x;
  int j = blockIdx.x, t = blockIdx.y, bh = blockIdx.z;
  int q = tid >> 2, ds = (tid & 3) * 16;
  float lc[3], L = 0.0f;
#pragma unroll
  for (int c = 0; c < 3; ++c) {
    lc[c] = Ml[((((size_t)c * 16 + bh) * 16 + j) * 2 + t) * 64 + q];
    L += lc[c];
  }
  float O[16];
#pragma unroll
  for (int i = 0; i < 16; ++i) O[i] = 0.0f;
#pragma unroll
  for (int c = 0; c < 3; ++c) {
    if (lc[c] > 0.0f) {
      size_t pb = ((((size_t)c * 16 + bh) * 16 + j) * 2 + t) * 4096 + q * 64 + ds;
      union { bf16x8 v; u16 e[8]; } a, b;
      a.v = *(const bf16x8*)(Pp + pb);
      b.v = *(const bf16x8*)(Pp + pb + 8);
#pragma unroll
      for (int i = 0; i < 8; ++i) {
        O[i]     += bf2f(a.e[i]);
        O[i + 8] += bf2f(b.e[i]);
      }
    }
  }
  float inv = 1.0f / L;
  int tile_abs = t ? (31 - j) : j;
  int s = tile_abs * 64 + q;
  int b2 = bh >> 3, h = bh & 7;
  size_t row = ((size_t)(b2 * 2048 + s)) * 512 + h * 64 + ds;
  union { bf16x8 v; u16 e[8]; } o0, o1;
#pragma unroll
  for (int i = 0; i < 8; ++i) {
    o0.e[i] = f2bf(O[i] * inv);
    o1.e[i] = f2bf(O[i + 8] * inv);
  }
  *(bf16x8*)(Ob + row)     = o0.v;
  *(bf16x8*)(Ob + row + 8) = o1.v;
}

// ---------------- out_proj GEMM: out = O @ w_out^T + b_out (fp32 out) ----------------
__global__ __launch_bounds__(256) void outproj_gemm(
    const u16* __restrict__ Ob, const u16* __restrict__ wb,
    const float* __restrict__ bout, float* __restrict__ out) {
  const int K = 512;
  __shared__ u16 At[2][64 * 32];
  __shared__ u16 Bt[2][128 * 32];
  int tid = threadIdx.x;
  int w = tid >> 6, lane = tid & 63;
  int ql = lane & 15, quad = lane >> 4;
  int wr = w >> 1, wc = w & 1;
  int mtile = blockIdx.x * 64, ntile = blockIdx.y * 128;

  int r4 = lane >> 2, c4 = lane & 3;
  int swz4 = c4 ^ (r4 & 3);

  const u16* ag0 = Ob + (size_t)(mtile + w * 16 + r4) * K + swz4 * 8;
  const u16* bg0 = wb + (size_t)(ntile + w * 32 + r4) * K + swz4 * 8;

  f32x4 acc[2][4];
#pragma unroll
  for (int t = 0; t < 2; ++t)
#pragma unroll
    for (int u = 0; u < 4; ++u) acc[t][u] = (f32x4){0, 0, 0, 0};

  lds_cp16(&At[0][w * 512], ag0);
  lds_cp16(&Bt[0][w * 1024], bg0);
  lds_cp16(&Bt[0][w * 1024 + 512], bg0 + 16 * K);

  int cb = ql & 3;
  for (int kk = 0; kk < 16; ++kk) {
    int cur = kk & 1;
    __syncthreads();
    if (kk < 15) {
      int k0 = (kk + 1) * 32;
      lds_cp16(&At[cur ^ 1][w * 512], ag0 + k0);
      lds_cp16(&Bt[cur ^ 1][w * 1024], bg0 + k0);
      lds_cp16(&Bt[cur ^ 1][w * 1024 + 512], bg0 + 16 * K + k0);
    }
    bf16x8 af[2], bf[4];
#pragma unroll
    for (int t = 0; t < 2; ++t) {
      int row = wr * 32 + t * 16 + ql;
      af[t] = *(const bf16x8*)(&At[cur][row * 32 + ((quad ^ cb) * 8)]);
    }
#pragma unroll
    for (int u = 0; u < 4; ++u) {
      int row = wc * 64 + u * 16 + ql;
      bf[u] = *(const bf16x8*)(&Bt[cur][row * 32 + ((quad ^ cb) * 8)]);
    }
#pragma unroll
    for (int t = 0; t < 2; ++t)
#pragma unroll
      for (int u = 0; u < 4; ++u)
        acc[t][u] = __builtin_amdgcn_mfma_f32_16x16x32_bf16(af[t], bf[u], acc[t][u], 0, 0, 0);
  }

#pragma unroll
  for (int u = 0; u < 4; ++u) {
    int n = ntile + wc * 64 + u * 16 + ql;
    float bias = bout[n];
#pragma unroll
    for (int t = 0; t < 2; ++t)
#pragma unroll
      for (int r = 0; r < 4; ++r) {
        int mm = mtile + wr * 32 + t * 16 + quad * 4 + r;
        out[(size_t)mm * 512 + n] = acc[t][u][r] + bias;
      }
  }
}

extern "C" void kernel_launch(void* const* d_in, const int* in_sizes, int n_in,
                              void* d_out, int out_size, void* d_ws, size_t ws_size,
                              hipStream_t stream) {
  const float* x     = (const float*)d_in[0];  // [2,2048,512]
  const float* w_in  = (const float*)d_in[1];  // [1536,512]
  const float* b_in  = (const float*)d_in[2];  // [1536]
  const float* w_out = (const float*)d_in[3];  // [512,512]
  const float* b_out = (const float*)d_in[4];  // [512]
  float* out = (float*)d_out;                  // [2,2048,512] fp32
  char* ws = (char*)d_ws;

  u16* xb    = (u16*)(ws);             // 4096x512 bf16   (4 MB)
  u16* winb  = (u16*)(ws + 4194304);   // 1536x512 bf16   (1.5 MB)
  u16* woutb = (u16*)(ws + 5767168);   // 512x512 bf16    (0.5 MB)
  u16* Qb    = (u16*)(ws + 6291456);   // [16][2048][64]  (4 MB)
  u16* Kb    = (u16*)(ws + 10485760);  // [16][2048][64]  (4 MB)
  u16* Vt    = (u16*)(ws + 14680064);  // [16][64][2048]  (4 MB)
  u16* Ob    = (u16*)(ws + 18874368);  // [4096][512]     (4 MB)
  u16* Pp    = (u16*)(ws + 23068672);  // [3][16][16][2][64][64] bf16 (12.6 MB)
  float* Ml  = (float*)(ws + 35651584); // [3][16][16][2][64] f32 (393 KB)

  cvt_all<<<3072, 256, 0, stream>>>((const float4*)x, (const float4*)w_in,
                                    (const float4*)w_out, xb, winb, woutb);
  inproj_gemm<<<dim3(32, 12), 256, 0, stream>>>(xb, winb, b_in, Qb, Kb, Vt);
  attn_kernel<<<dim3(16, 3, 16), 256, 0, stream>>>(Qb, Kb, Vt, Pp, Ml);
  attn_merge<<<dim3(16, 2, 16), 256, 0, stream>>>(Pp, Ml, Ob);
  outproj_gemm<<<dim3(64, 4), 256, 0, stream>>>(Ob, woutb, b_out, out);
}